// Round 19
// baseline (108.291 us; speedup 1.0000x reference)
//
#include <hip/hip_runtime.h>

#define CIN   256
#define COUT  256
#define HH    64
#define WW    64
#define KD    2304         // CIN * 9
#define NPIX  16384        // B * HO * WO
#define SPLIT 16
#define CPS   (CIN / SPLIT)
#define NSTEP 18           // K per quarter = 576 = 18 x 32

typedef __attribute__((ext_vector_type(4))) float  float4v;
typedef __attribute__((ext_vector_type(4))) unsigned int uint4v;
typedef _Float16 h2 __attribute__((ext_vector_type(2)));
typedef _Float16 h8 __attribute__((ext_vector_type(8)));
typedef unsigned int u32;
typedef unsigned short u16;

__device__ __forceinline__ h2 as_h2(u32 v) { union { u32 u; h2 h; } x; x.u = v; return x.h; }
__device__ __forceinline__ u32 as_u32(h2 h) { union { u32 u; h2 h; } x; x.h = h; return x.u; }
__device__ __forceinline__ u16 f2h_bits(float f) { _Float16 h = (_Float16)f; return *(u16*)&h; }
__device__ __forceinline__ u32 packh2(float a, float b) {
  h2 h; h[0] = (_Float16)a; h[1] = (_Float16)b; return as_u32(h);
}

__device__ __forceinline__ void gload_lds16(const void* g, void* l) {
  __builtin_amdgcn_global_load_lds((const __attribute__((address_space(1))) u32*)g,
                                   (__attribute__((address_space(3))) u32*)l, 16, 0, 0);
}

// ---------------- Kernel 1a: offset/mask partials (f16-packed) + xt emission ----------------
__global__ __launch_bounds__(256) void offmask_part_kernel(
    const float* __restrict__ x,
    const float* __restrict__ off_dw, const float* __restrict__ off_pw,
    const float* __restrict__ mask_dw, const float* __restrict__ mask_pw,
    u32* __restrict__ part2, u16* __restrict__ xt)
{
  int m = blockIdx.x * 256 + threadIdx.x;
  int s = blockIdx.y;
  int b = m >> 12, pix = m & 4095;
  int ho = pix >> 6, wo = pix & 63;
  const float* xb = x + (size_t)b * CIN * 4096;

  float acc[27];
#pragma unroll
  for (int j = 0; j < 27; ++j) acc[j] = 0.f;
  u16 ctr[16];

  int c0 = s * CPS;
  for (int ci = 0; ci < CPS; ++ci) {
    int c = c0 + ci;
    const float* xc = xb + (size_t)c * 4096;
    float d_off = 0.f, d_msk = 0.f;
#pragma unroll
    for (int t = 0; t < 9; ++t) {
      int gy = ho + t / 3 - 1, gx = wo + t % 3 - 1;
      bool ok = (gy >= 0) & (gy < HH) & (gx >= 0) & (gx < WW);
      float v = ok ? xc[gy * 64 + gx] : 0.f;
      if (t == 4) ctr[ci] = f2h_bits(v);
      d_off += v * off_dw[c * 9 + t];
      d_msk += v * mask_dw[c * 9 + t];
    }
#pragma unroll
    for (int j = 0; j < 18; ++j) acc[j] += d_off * off_pw[j * 256 + c];
#pragma unroll
    for (int j = 0; j < 9; ++j) acc[18 + j] += d_msk * mask_pw[j * 256 + c];
  }
  *(uint4v*)(xt + (size_t)m * 256 + c0)     = *(uint4v*)&ctr[0];
  *(uint4v*)(xt + (size_t)m * 256 + c0 + 8) = *(uint4v*)&ctr[8];

  uint4v o[4];
#pragma unroll
  for (int k = 0; k < 13; ++k) o[k >> 2][k & 3] = packh2(acc[2 * k], acc[2 * k + 1]);
  o[3][1] = packh2(acc[26], 0.f);
  o[3][2] = 0; o[3][3] = 0;
  uint4v* pp = (uint4v*)(part2 + ((size_t)s * NPIX + m) * 16);
#pragma unroll
  for (int q = 0; q < 4; ++q) pp[q] = o[q];
}

// ---------------- Kernel 1b: reduce f16 partials -> rec f32 ----------------
__global__ __launch_bounds__(256) void offmask_reduce_kernel(
    const u32* __restrict__ part2, float* __restrict__ rec)
{
  int i = blockIdx.x * 256 + threadIdx.x;   // over NPIX*16
  int m = i >> 4, k = i & 15;
  int j0 = 2 * k, j1 = 2 * k + 1;
  if (j0 >= 27) { rec[(size_t)m * 32 + j0] = 0.f; rec[(size_t)m * 32 + j1] = 0.f; return; }
  float s0 = 0.f, s1 = 0.f;
#pragma unroll
  for (int s = 0; s < SPLIT; ++s) {
    h2 v = as_h2(part2[((size_t)s * NPIX + m) * 16 + k]);
    s0 += (float)v[0]; s1 += (float)v[1];
  }
  rec[(size_t)m * 32 + j0] = (j0 < 18) ? s0 : 2.f / (1.f + __expf(-s0));
  rec[(size_t)m * 32 + j1] = (j1 < 18) ? s1 : ((j1 < 27) ? 2.f / (1.f + __expf(-s1)) : 0.f);
}

// ---------------- Kernel 2: weight f32 -> f16 [co][kk*256 + c] ----------------
__global__ __launch_bounds__(256) void wconv_kernel(const float* __restrict__ w,
                                                    u16* __restrict__ wb)
{
  int i = blockIdx.x * 256 + threadIdx.x;
  int co = i / KD, rem = i - co * KD;
  int c = rem / 9, kk = rem - c * 9;
  wb[co * KD + kk * 256 + c] = f2h_bits(w[i]);
}

// ---------------- Kernel 4: FUSED im2col+GEMM, FAT TILE, L1-grouped sampling ----------------
// R17/R14 core; ONLY the B-sampling lane layout changes: 4 consecutive lanes
// cover one pixel's 64B (slices s4=0..3 x 16B), each thread handles 2 pixels
// (pxA, pxA+128). Per corner-instruction a wave touches 16 L1 lines (64B
// consecutive per pixel) instead of 32 -> sample L1 transactions halved at
// identical bytes / instruction count / vmcnt ledger (8 loads -> vmcnt(2)).
__global__ __launch_bounds__(512, 2) void gemm_fused_kernel(
    const u16* __restrict__ A,     // wb f16 [COUT][KD]
    const u16* __restrict__ xt,    // NHWC f16 [B*4096][256]
    const float* __restrict__ rec, // [NPIX][32]
    u16* __restrict__ tmp4)        // [4][B][COUT][4096] f16 partials
{
  __shared__ __align__(16) u16 lA[3][256 * 32];   // 3 x 16 KB
  __shared__ __align__(16) u16 lB[2][256 * 32];   // 2 x 16 KB
  const int tid = threadIdx.x;
  const int ord = blockIdx.x;            // 0..255
  const int xcd = ord & 7, slot = ord >> 3;
  const int ptile = (slot >> 2) * 8 + xcd;   // 0..63 (bijective remap)
  const int h     = slot & 3;                // K quarter
  const int m0  = ptile * 256;
  const int b_img = ptile >> 4;
  const int cbase = h * 64;
  const int wave = tid >> 6, lane = tid & 63;
  const int wm = wave >> 1, wn = wave & 1;
  const int rl = lane & 15, kq = lane >> 4;
  const int sA = (kq ^ (rl & 3) ^ ((rl >> 2) & 3)) * 8;

  const int rA  = tid >> 2;
  const int koA = ((tid & 3) ^ (rA & 3) ^ ((rA >> 2) & 3)) * 8;
  const u16* aRow0 = A + (size_t)rA * KD + koA;
  const u16* aRow1 = A + (size_t)(rA + 128) * KD + koA;

  // B sampling: thread -> 2 pixels (pxA = tid>>2, pxB = pxA+128), slice s4 (8ch/16B)
  const int s4  = tid & 3;
  const int pxA = tid >> 2;              // 0..127
  const int pxB = pxA + 128;
  const int mA = m0 + pxA, mB = m0 + pxB;
  const int hoA = (mA & 4095) >> 6, woA = mA & 63;
  const int hoB = (mB & 4095) >> 6, woB = mB & 63;
  const float* rpA = rec + (size_t)mA * 32;
  const float* rpB = rec + (size_t)mB * 32;
  const u16* xb = xt + (size_t)b_img * 4096 * 256;
  const int swzA = (pxA & 3) ^ ((pxA >> 2) & 3);
  const int swzB = (pxB & 3) ^ ((pxB >> 2) & 3);
  const int wAddrA = pxA * 32 + ((s4 ^ swzA) * 8);
  const int wAddrB = pxB * 32 + ((s4 ^ swzB) * 8);

  u32 cOffA[4], cOffB[4];
  h2  whA[4], whB[4];

#define KCOL(t_) (((t_) >> 1) * 256 + cbase + ((t_) & 1) * 32)

#define CALC_CORNERS1(kk_, rp_, ho_, wo_, cOff_, wh_) do {                 \
    float dy = rp_[(kk_) * 2], dx = rp_[(kk_) * 2 + 1], msk = rp_[18 + (kk_)];\
    float py  = (float)(ho_ - 1 + ((kk_) / 3)) + dy;                       \
    float pxf = (float)(wo_ - 1 + ((kk_) % 3)) + dx;                       \
    float fy = floorf(py), fx = floorf(pxf);                               \
    int y0 = (int)fy, x0 = (int)fx;                                        \
    float wy1 = py - fy, wy0 = 1.f - wy1;                                  \
    float wx1 = pxf - fx, wx0 = 1.f - wx1;                                 \
    _Pragma("unroll")                                                      \
    for (int cr = 0; cr < 4; ++cr) {                                       \
      int iy = y0 + (cr >> 1), ix = x0 + (cr & 1);                         \
      bool valid = (iy >= 0) & (iy < HH) & (ix >= 0) & (ix < WW);          \
      int iyc = min(max(iy, 0), HH - 1), ixc = min(max(ix, 0), WW - 1);    \
      cOff_[cr] = (u32)(iyc * 64 + ixc) * 256;                             \
      float wy = (cr >> 1) ? wy1 : wy0;                                    \
      float wx = (cr & 1) ? wx1 : wx0;                                     \
      float wf = valid ? (wy * wx * msk) : 0.f;                            \
      _Float16 hw = (_Float16)wf;                                          \
      wh_[cr] = (h2){hw, hw};                                              \
    }                                                                      \
  } while (0)

#define CALC_CORNERS(kk_) do {                                             \
    CALC_CORNERS1(kk_, rpA, hoA, woA, cOffA, whA);                         \
    CALC_CORNERS1(kk_, rpB, hoB, woB, cOffB, whB);                         \
  } while (0)

#define STAGE_A(k_, slot_) do {                                            \
    int k0_ = KCOL(k_);                                                    \
    gload_lds16(aRow0 + k0_, lA[slot_] + tid * 8);                         \
    gload_lds16(aRow1 + k0_, lA[slot_] + (tid + 512) * 8);                 \
  } while (0)

  // samples: 4 corners x 16B for each of the two pixels (8 loads total)
#define SAMP_LOAD(t_, va, vb) do {                                         \
    int c0n_ = cbase + ((t_) & 1) * 32 + s4 * 8;                           \
    _Pragma("unroll")                                                      \
    for (int cr = 0; cr < 4; ++cr) {                                       \
      va[cr] = *(const uint4v*)(xb + cOffA[cr] + c0n_);                    \
      vb[cr] = *(const uint4v*)(xb + cOffB[cr] + c0n_);                    \
    }                                                                      \
  } while (0)

#define BLEND_WRITE(bufi_, va, vb) do {                                    \
    uint4v o0, o1;                                                         \
    _Pragma("unroll")                                                      \
    for (int w_ = 0; w_ < 4; ++w_) {                                       \
      h2 s0_ = whA[0] * as_h2(va[0][w_]) + whA[1] * as_h2(va[1][w_]);      \
      s0_   += whA[2] * as_h2(va[2][w_]) + whA[3] * as_h2(va[3][w_]);      \
      h2 s1_ = whB[0] * as_h2(vb[0][w_]) + whB[1] * as_h2(vb[1][w_]);      \
      s1_   += whB[2] * as_h2(vb[2][w_]) + whB[3] * as_h2(vb[3][w_]);      \
      o0[w_] = as_u32(s0_); o1[w_] = as_u32(s1_);                          \
    }                                                                      \
    *(uint4v*)&lB[bufi_][wAddrA] = o0;                                     \
    *(uint4v*)&lB[bufi_][wAddrB] = o1;                                     \
  } while (0)

  float4v acc[4][8];
#pragma unroll
  for (int m = 0; m < 4; ++m)
#pragma unroll
    for (int n = 0; n < 8; ++n) acc[m][n] = float4v{0.f, 0.f, 0.f, 0.f};

  // ---- prologue: SAMP(0)[8] -> A(0)[2] -> A(1)[2]; vmcnt(2) keeps A(1) ----
  {
    CALC_CORNERS(0);
    uint4v va[4], vb[4];
    SAMP_LOAD(0, va, vb);
    STAGE_A(0, 0);
    STAGE_A(1, 1);
    asm volatile("s_waitcnt vmcnt(2)" ::: "memory");
    BLEND_WRITE(0, va, vb);
    asm volatile("s_waitcnt lgkmcnt(0)" ::: "memory");
    __builtin_amdgcn_s_barrier();
  }

  for (int it = 0; it < 3; ++it) {
#pragma unroll
    for (int u = 0; u < 6; ++u) {
      const int t = it * 6 + u;
      const int tn  = (t + 1 == NSTEP) ? 0 : t + 1;
      const int tn2 = (t + 2 >= NSTEP) ? (t + 2 - NSTEP) : t + 2;
      if ((tn & 1) == 0) CALC_CORNERS(tn >> 1);
      uint4v va[4], vb[4];
      SAMP_LOAD(tn, va, vb);
      STAGE_A(tn2, (u + 2) % 3);
      h8 af[4], bf[8];
#pragma unroll
      for (int m = 0; m < 4; ++m)
        af[m] = *(const h8*)&lA[u % 3][(wm * 64 + m * 16 + rl) * 32 + sA];
#pragma unroll
      for (int n = 0; n < 8; ++n)
        bf[n] = *(const h8*)&lB[u & 1][(wn * 128 + n * 16 + rl) * 32 + sA];
#pragma unroll
      for (int m = 0; m < 4; ++m)
#pragma unroll
        for (int n = 0; n < 8; ++n)
          acc[m][n] = __builtin_amdgcn_mfma_f32_16x16x32_f16(af[m], bf[n], acc[m][n], 0, 0, 0);
      asm volatile("s_waitcnt vmcnt(2)" ::: "memory");
      BLEND_WRITE((u + 1) & 1, va, vb);
      asm volatile("s_waitcnt lgkmcnt(0)" ::: "memory");
      __builtin_amdgcn_s_barrier();
    }
  }
#undef STAGE_A
#undef CALC_CORNERS
#undef CALC_CORNERS1
#undef SAMP_LOAD
#undef BLEND_WRITE
#undef KCOL

  const int p_base = (m0 & 4095) + wn * 128;
  u16* db = tmp4 + (size_t)h * COUT * NPIX + (size_t)b_img * COUT * 4096;
#pragma unroll
  for (int m = 0; m < 4; ++m) {
#pragma unroll
    for (int j = 0; j < 4; ++j) {
      int co = wm * 64 + m * 16 + kq * 4 + j;
#pragma unroll
      for (int n = 0; n < 8; ++n) {
        int pp = p_base + n * 16 + rl;
        db[(size_t)co * 4096 + pp] = f2h_bits(acc[m][n][j]);
      }
    }
  }
}

// ---------------- Kernel 5: out = bias + sum of 4 f16 quarter-tiles ----------------
__global__ __launch_bounds__(256) void add_kernel(const u16* __restrict__ tmp4,
                                                  const float* __restrict__ bias,
                                                  float* __restrict__ out)
{
  size_t i = ((size_t)blockIdx.x * 256 + threadIdx.x) * 8;  // over COUT*NPIX
  int co = (int)((i >> 12) & 255);
  float bv = bias[co];
  uint4v v0 = *(const uint4v*)(tmp4 + i);
  uint4v v1 = *(const uint4v*)(tmp4 + (size_t)COUT * NPIX + i);
  uint4v v2 = *(const uint4v*)(tmp4 + (size_t)2 * COUT * NPIX + i);
  uint4v v3 = *(const uint4v*)(tmp4 + (size_t)3 * COUT * NPIX + i);
  float4v oA, oB;
#pragma unroll
  for (int w = 0; w < 4; ++w) {
    h2 a = as_h2(v0[w]), b = as_h2(v1[w]), c = as_h2(v2[w]), d = as_h2(v3[w]);
    float lo = (float)a[0] + (float)b[0] + (float)c[0] + (float)d[0] + bv;
    float hi = (float)a[1] + (float)b[1] + (float)c[1] + (float)d[1] + bv;
    if (w < 2) { oA[w * 2] = lo; oA[w * 2 + 1] = hi; }
    else       { oB[(w - 2) * 2] = lo; oB[(w - 2) * 2 + 1] = hi; }
  }
  *(float4v*)(out + i) = oA;
  *(float4v*)(out + i + 4) = oB;
}

extern "C" void kernel_launch(void* const* d_in, const int* in_sizes, int n_in,
                              void* d_out, int out_size, void* d_ws, size_t ws_size,
                              hipStream_t stream) {
  const float* x       = (const float*)d_in[0];
  const float* weight  = (const float*)d_in[1];
  const float* bias    = (const float*)d_in[2];
  const float* off_dw  = (const float*)d_in[3];
  const float* off_pw  = (const float*)d_in[4];
  const float* mask_dw = (const float*)d_in[5];
  const float* mask_pw = (const float*)d_in[6];

  // ws layout: rec 2MB @0 | wb 1.18MB @2,097,152 | xt 8.39MB @3,276,800 |
  //            @11,665,408: part2 16.78MB (consumed by reduce), then tmp4
  //            33.55MB aliases it (written by gemm AFTER reduce ran).
  //            total = 45,219,840 B
  if (ws_size < 45219840ull) return;
  float* rec   = (float*)d_ws;
  u16*   wb    = (u16*)((char*)d_ws + 2097152);
  u16*   xt    = (u16*)((char*)d_ws + 3276800);
  u32*   part2 = (u32*)((char*)d_ws + 11665408);
  u16*   tmp4  = (u16*)((char*)d_ws + 11665408);
  float* out   = (float*)d_out;

  wconv_kernel<<<dim3(2304), dim3(256), 0, stream>>>(weight, wb);
  offmask_part_kernel<<<dim3(NPIX / 256, SPLIT), dim3(256), 0, stream>>>(
      x, off_dw, off_pw, mask_dw, mask_pw, part2, xt);
  offmask_reduce_kernel<<<dim3(NPIX * 16 / 256), dim3(256), 0, stream>>>(part2, rec);
  gemm_fused_kernel<<<dim3(256), dim3(512), 0, stream>>>(wb, xt, rec, tmp4);
  add_kernel<<<dim3(COUT * NPIX / 8 / 256), dim3(256), 0, stream>>>(tmp4, bias, out);
}

// Round 20
// 93.658 us; speedup vs baseline: 1.1562x; 1.1562x over previous
//
#include <hip/hip_runtime.h>

#define CIN   256
#define COUT  256
#define HH    64
#define WW    64
#define KD    2304         // CIN * 9
#define NPIX  16384        // B * HO * WO
#define SPLIT 16
#define CPS   (CIN / SPLIT)
#define NSTEP 18           // K per quarter = 576 = 18 x 32

typedef __attribute__((ext_vector_type(4))) float  float4v;
typedef __attribute__((ext_vector_type(4))) unsigned int uint4v;
typedef _Float16 h2 __attribute__((ext_vector_type(2)));
typedef _Float16 h8 __attribute__((ext_vector_type(8)));
typedef unsigned int u32;
typedef unsigned short u16;

__device__ __forceinline__ h2 as_h2(u32 v) { union { u32 u; h2 h; } x; x.u = v; return x.h; }
__device__ __forceinline__ u32 as_u32(h2 h) { union { u32 u; h2 h; } x; x.h = h; return x.u; }
__device__ __forceinline__ u16 f2h_bits(float f) { _Float16 h = (_Float16)f; return *(u16*)&h; }
__device__ __forceinline__ u32 packh2(float a, float b) {
  h2 h; h[0] = (_Float16)a; h[1] = (_Float16)b; return as_u32(h);
}

__device__ __forceinline__ void gload_lds16(const void* g, void* l) {
  __builtin_amdgcn_global_load_lds((const __attribute__((address_space(1))) u32*)g,
                                   (__attribute__((address_space(3))) u32*)l, 16, 0, 0);
}

// ---------------- Kernel 1a: offset/mask partials (f16-packed) + xt emission ----------------
// Fused xpose: thread (pixel m, split s) owns channels s*16..s*16+15 and writes
// their f16 center values to xt[m*256 + s*16] — x is read once total.
__global__ __launch_bounds__(256) void offmask_part_kernel(
    const float* __restrict__ x,
    const float* __restrict__ off_dw, const float* __restrict__ off_pw,
    const float* __restrict__ mask_dw, const float* __restrict__ mask_pw,
    u32* __restrict__ part2, u16* __restrict__ xt)
{
  int m = blockIdx.x * 256 + threadIdx.x;
  int s = blockIdx.y;
  int b = m >> 12, pix = m & 4095;
  int ho = pix >> 6, wo = pix & 63;
  const float* xb = x + (size_t)b * CIN * 4096;

  float acc[27];
#pragma unroll
  for (int j = 0; j < 27; ++j) acc[j] = 0.f;
  u16 ctr[16];

  int c0 = s * CPS;
  for (int ci = 0; ci < CPS; ++ci) {
    int c = c0 + ci;
    const float* xc = xb + (size_t)c * 4096;
    float d_off = 0.f, d_msk = 0.f;
#pragma unroll
    for (int t = 0; t < 9; ++t) {
      int gy = ho + t / 3 - 1, gx = wo + t % 3 - 1;
      bool ok = (gy >= 0) & (gy < HH) & (gx >= 0) & (gx < WW);
      float v = ok ? xc[gy * 64 + gx] : 0.f;
      if (t == 4) ctr[ci] = f2h_bits(v);
      d_off += v * off_dw[c * 9 + t];
      d_msk += v * mask_dw[c * 9 + t];
    }
#pragma unroll
    for (int j = 0; j < 18; ++j) acc[j] += d_off * off_pw[j * 256 + c];
#pragma unroll
    for (int j = 0; j < 9; ++j) acc[18 + j] += d_msk * mask_pw[j * 256 + c];
  }
  *(uint4v*)(xt + (size_t)m * 256 + c0)     = *(uint4v*)&ctr[0];
  *(uint4v*)(xt + (size_t)m * 256 + c0 + 8) = *(uint4v*)&ctr[8];

  uint4v o[4];
#pragma unroll
  for (int k = 0; k < 13; ++k) o[k >> 2][k & 3] = packh2(acc[2 * k], acc[2 * k + 1]);
  o[3][1] = packh2(acc[26], 0.f);
  o[3][2] = 0; o[3][3] = 0;
  uint4v* pp = (uint4v*)(part2 + ((size_t)s * NPIX + m) * 16);
#pragma unroll
  for (int q = 0; q < 4; ++q) pp[q] = o[q];
}

// ---------------- Kernel 1b: reduce f16 partials -> rec f32 ----------------
__global__ __launch_bounds__(256) void offmask_reduce_kernel(
    const u32* __restrict__ part2, float* __restrict__ rec)
{
  int i = blockIdx.x * 256 + threadIdx.x;   // over NPIX*16
  int m = i >> 4, k = i & 15;
  int j0 = 2 * k, j1 = 2 * k + 1;
  if (j0 >= 27) { rec[(size_t)m * 32 + j0] = 0.f; rec[(size_t)m * 32 + j1] = 0.f; return; }
  float s0 = 0.f, s1 = 0.f;
#pragma unroll
  for (int s = 0; s < SPLIT; ++s) {
    h2 v = as_h2(part2[((size_t)s * NPIX + m) * 16 + k]);
    s0 += (float)v[0]; s1 += (float)v[1];
  }
  rec[(size_t)m * 32 + j0] = (j0 < 18) ? s0 : 2.f / (1.f + __expf(-s0));
  rec[(size_t)m * 32 + j1] = (j1 < 18) ? s1 : ((j1 < 27) ? 2.f / (1.f + __expf(-s1)) : 0.f);
}

// ---------------- Kernel 2: weight f32 -> f16 [co][kk*256 + c] ----------------
__global__ __launch_bounds__(256) void wconv_kernel(const float* __restrict__ w,
                                                    u16* __restrict__ wb)
{
  int i = blockIdx.x * 256 + threadIdx.x;
  int co = i / KD, rem = i - co * KD;
  int c = rem / 9, kk = rem - c * 9;
  wb[co * KD + kk * 256 + c] = f2h_bits(w[i]);
}

// ---------------- Kernel 4: FUSED im2col+GEMM, FAT TILE (proven R14/R17 core) ----------------
__global__ __launch_bounds__(512, 2) void gemm_fused_kernel(
    const u16* __restrict__ A,     // wb f16 [COUT][KD]
    const u16* __restrict__ xt,    // NHWC f16 [B*4096][256]
    const float* __restrict__ rec, // [NPIX][32]
    u16* __restrict__ tmp4)        // [4][B][COUT][4096] f16 partials
{
  __shared__ __align__(16) u16 lA[3][256 * 32];   // 3 x 16 KB
  __shared__ __align__(16) u16 lB[2][256 * 32];   // 2 x 16 KB
  const int tid = threadIdx.x;
  const int ord = blockIdx.x;            // 0..255
  const int xcd = ord & 7, slot = ord >> 3;
  const int ptile = (slot >> 2) * 8 + xcd;   // 0..63 (bijective remap)
  const int h     = slot & 3;                // K quarter
  const int m0  = ptile * 256;
  const int b_img = ptile >> 4;
  const int cbase = h * 64;
  const int wave = tid >> 6, lane = tid & 63;
  const int wm = wave >> 1, wn = wave & 1;
  const int rl = lane & 15, kq = lane >> 4;
  const int sA = (kq ^ (rl & 3) ^ ((rl >> 2) & 3)) * 8;

  const int rA  = tid >> 2;
  const int koA = ((tid & 3) ^ (rA & 3) ^ ((rA >> 2) & 3)) * 8;
  const u16* aRow0 = A + (size_t)rA * KD + koA;
  const u16* aRow1 = A + (size_t)(rA + 128) * KD + koA;

  const int px_t = tid >> 1;             // 0..255
  const int chh  = (tid & 1) * 16;       // 0 or 16
  const int m_px = m0 + px_t;
  const int ho = (m_px & 4095) >> 6, wo = m_px & 63;
  const float* rp = rec + (size_t)m_px * 32;
  const u16* xb = xt + (size_t)b_img * 4096 * 256;
  const int swzp = (px_t & 3) ^ ((px_t >> 2) & 3);
  const int wAddr0 = px_t * 32 + ((((tid & 1) * 2)     ^ swzp) * 8);
  const int wAddr1 = px_t * 32 + ((((tid & 1) * 2 + 1) ^ swzp) * 8);

  u32 cOff[4];
  h2  wh[4];

#define KCOL(t_) (((t_) >> 1) * 256 + cbase + ((t_) & 1) * 32)

#define CALC_CORNERS(kk_) do {                                             \
    float dy = rp[(kk_) * 2], dx = rp[(kk_) * 2 + 1], msk = rp[18 + (kk_)];\
    float py  = (float)(ho - 1 + ((kk_) / 3)) + dy;                        \
    float pxf = (float)(wo - 1 + ((kk_) % 3)) + dx;                        \
    float fy = floorf(py), fx = floorf(pxf);                               \
    int y0 = (int)fy, x0 = (int)fx;                                        \
    float wy1 = py - fy, wy0 = 1.f - wy1;                                  \
    float wx1 = pxf - fx, wx0 = 1.f - wx1;                                 \
    _Pragma("unroll")                                                      \
    for (int cr = 0; cr < 4; ++cr) {                                       \
      int iy = y0 + (cr >> 1), ix = x0 + (cr & 1);                         \
      bool valid = (iy >= 0) & (iy < HH) & (ix >= 0) & (ix < WW);          \
      int iyc = min(max(iy, 0), HH - 1), ixc = min(max(ix, 0), WW - 1);    \
      cOff[cr] = (u32)(iyc * 64 + ixc) * 256;                              \
      float wy = (cr >> 1) ? wy1 : wy0;                                    \
      float wx = (cr & 1) ? wx1 : wx0;                                     \
      float wf = valid ? (wy * wx * msk) : 0.f;                            \
      _Float16 hw = (_Float16)wf;                                          \
      wh[cr] = (h2){hw, hw};                                               \
    }                                                                      \
  } while (0)

#define STAGE_A(k_, slot_) do {                                            \
    int k0_ = KCOL(k_);                                                    \
    gload_lds16(aRow0 + k0_, lA[slot_] + tid * 8);                         \
    gload_lds16(aRow1 + k0_, lA[slot_] + (tid + 512) * 8);                 \
  } while (0)

#define SAMP_LOAD(t_, va, vb) do {                                         \
    int c0n_ = cbase + ((t_) & 1) * 32 + chh;                              \
    _Pragma("unroll")                                                      \
    for (int cr = 0; cr < 4; ++cr) {                                       \
      va[cr] = *(const uint4v*)(xb + cOff[cr] + c0n_);                     \
      vb[cr] = *(const uint4v*)(xb + cOff[cr] + c0n_ + 8);                 \
    }                                                                      \
  } while (0)

#define BLEND_WRITE(bufi_, va, vb) do {                                    \
    uint4v o0, o1;                                                         \
    _Pragma("unroll")                                                      \
    for (int w_ = 0; w_ < 4; ++w_) {                                       \
      h2 s0_ = wh[0] * as_h2(va[0][w_]) + wh[1] * as_h2(va[1][w_]);        \
      s0_   += wh[2] * as_h2(va[2][w_]) + wh[3] * as_h2(va[3][w_]);        \
      h2 s1_ = wh[0] * as_h2(vb[0][w_]) + wh[1] * as_h2(vb[1][w_]);        \
      s1_   += wh[2] * as_h2(vb[2][w_]) + wh[3] * as_h2(vb[3][w_]);        \
      o0[w_] = as_u32(s0_); o1[w_] = as_u32(s1_);                          \
    }                                                                      \
    *(uint4v*)&lB[bufi_][wAddr0] = o0;                                     \
    *(uint4v*)&lB[bufi_][wAddr1] = o1;                                     \
  } while (0)

  float4v acc[4][8];
#pragma unroll
  for (int m = 0; m < 4; ++m)
#pragma unroll
    for (int n = 0; n < 8; ++n) acc[m][n] = float4v{0.f, 0.f, 0.f, 0.f};

  // ---- prologue ----
  {
    CALC_CORNERS(0);
    uint4v va[4], vb[4];
    SAMP_LOAD(0, va, vb);
    STAGE_A(0, 0);
    STAGE_A(1, 1);
    asm volatile("s_waitcnt vmcnt(2)" ::: "memory");
    BLEND_WRITE(0, va, vb);
    asm volatile("s_waitcnt lgkmcnt(0)" ::: "memory");
    __builtin_amdgcn_s_barrier();
  }

  for (int it = 0; it < 3; ++it) {
#pragma unroll
    for (int u = 0; u < 6; ++u) {
      const int t = it * 6 + u;
      const int tn  = (t + 1 == NSTEP) ? 0 : t + 1;
      const int tn2 = (t + 2 >= NSTEP) ? (t + 2 - NSTEP) : t + 2;
      if ((tn & 1) == 0) CALC_CORNERS(tn >> 1);
      uint4v va[4], vb[4];
      SAMP_LOAD(tn, va, vb);
      STAGE_A(tn2, (u + 2) % 3);
      h8 af[4], bf[8];
#pragma unroll
      for (int m = 0; m < 4; ++m)
        af[m] = *(const h8*)&lA[u % 3][(wm * 64 + m * 16 + rl) * 32 + sA];
#pragma unroll
      for (int n = 0; n < 8; ++n)
        bf[n] = *(const h8*)&lB[u & 1][(wn * 128 + n * 16 + rl) * 32 + sA];
#pragma unroll
      for (int m = 0; m < 4; ++m)
#pragma unroll
        for (int n = 0; n < 8; ++n)
          acc[m][n] = __builtin_amdgcn_mfma_f32_16x16x32_f16(af[m], bf[n], acc[m][n], 0, 0, 0);
      asm volatile("s_waitcnt vmcnt(2)" ::: "memory");
      BLEND_WRITE((u + 1) & 1, va, vb);
      asm volatile("s_waitcnt lgkmcnt(0)" ::: "memory");
      __builtin_amdgcn_s_barrier();
    }
  }
#undef STAGE_A
#undef CALC_CORNERS
#undef SAMP_LOAD
#undef BLEND_WRITE
#undef KCOL

  const int p_base = (m0 & 4095) + wn * 128;
  u16* db = tmp4 + (size_t)h * COUT * NPIX + (size_t)b_img * COUT * 4096;
#pragma unroll
  for (int m = 0; m < 4; ++m) {
#pragma unroll
    for (int j = 0; j < 4; ++j) {
      int co = wm * 64 + m * 16 + kq * 4 + j;
#pragma unroll
      for (int n = 0; n < 8; ++n) {
        int pp = p_base + n * 16 + rl;
        db[(size_t)co * 4096 + pp] = f2h_bits(acc[m][n][j]);
      }
    }
  }
}

// ---------------- Kernel 5: out = bias + sum of 4 f16 quarter-tiles ----------------
__global__ __launch_bounds__(256) void add_kernel(const u16* __restrict__ tmp4,
                                                  const float* __restrict__ bias,
                                                  float* __restrict__ out)
{
  size_t i = ((size_t)blockIdx.x * 256 + threadIdx.x) * 8;  // over COUT*NPIX
  int co = (int)((i >> 12) & 255);
  float bv = bias[co];
  uint4v v0 = *(const uint4v*)(tmp4 + i);
  uint4v v1 = *(const uint4v*)(tmp4 + (size_t)COUT * NPIX + i);
  uint4v v2 = *(const uint4v*)(tmp4 + (size_t)2 * COUT * NPIX + i);
  uint4v v3 = *(const uint4v*)(tmp4 + (size_t)3 * COUT * NPIX + i);
  float4v oA, oB;
#pragma unroll
  for (int w = 0; w < 4; ++w) {
    h2 a = as_h2(v0[w]), b = as_h2(v1[w]), c = as_h2(v2[w]), d = as_h2(v3[w]);
    float lo = (float)a[0] + (float)b[0] + (float)c[0] + (float)d[0] + bv;
    float hi = (float)a[1] + (float)b[1] + (float)c[1] + (float)d[1] + bv;
    if (w < 2) { oA[w * 2] = lo; oA[w * 2 + 1] = hi; }
    else       { oB[(w - 2) * 2] = lo; oB[(w - 2) * 2 + 1] = hi; }
  }
  *(float4v*)(out + i) = oA;
  *(float4v*)(out + i + 4) = oB;
}

extern "C" void kernel_launch(void* const* d_in, const int* in_sizes, int n_in,
                              void* d_out, int out_size, void* d_ws, size_t ws_size,
                              hipStream_t stream) {
  const float* x       = (const float*)d_in[0];
  const float* weight  = (const float*)d_in[1];
  const float* bias    = (const float*)d_in[2];
  const float* off_dw  = (const float*)d_in[3];
  const float* off_pw  = (const float*)d_in[4];
  const float* mask_dw = (const float*)d_in[5];
  const float* mask_pw = (const float*)d_in[6];

  // ws layout: rec 2MB @0 | wb 1.18MB @2,097,152 | xt 8.39MB @3,276,800 |
  //            @11,665,408: part2 16.78MB (consumed by reduce), then tmp4
  //            33.55MB aliases it (written by gemm AFTER reduce ran).
  //            total = 45,219,840 B
  if (ws_size < 45219840ull) return;
  float* rec   = (float*)d_ws;
  u16*   wb    = (u16*)((char*)d_ws + 2097152);
  u16*   xt    = (u16*)((char*)d_ws + 3276800);
  u32*   part2 = (u32*)((char*)d_ws + 11665408);
  u16*   tmp4  = (u16*)((char*)d_ws + 11665408);
  float* out   = (float*)d_out;

  wconv_kernel<<<dim3(2304), dim3(256), 0, stream>>>(weight, wb);
  offmask_part_kernel<<<dim3(NPIX / 256, SPLIT), dim3(256), 0, stream>>>(
      x, off_dw, off_pw, mask_dw, mask_pw, part2, xt);
  offmask_reduce_kernel<<<dim3(NPIX * 16 / 256), dim3(256), 0, stream>>>(part2, rec);
  gemm_fused_kernel<<<dim3(256), dim3(512), 0, stream>>>(wb, xt, rec, tmp4);
  add_kernel<<<dim3(COUT * NPIX / 8 / 256), dim3(256), 0, stream>>>(tmp4, bias, out);
}